// Round 1
// baseline (1999.717 us; speedup 1.0000x reference)
//
#include <hip/hip_runtime.h>
#include <hip/hip_bf16.h>
#include <stdio.h>

#define DIM 2048
#define HID 2730
#define HID_PAD 2816   // 22*128, zero-padded
#define NE 8
#define NTOK 8192      // B*T
#define NROWS 24576    // 16384 expert-assignment rows + 8192 shared rows
#define BM 128
#define BN 128
#define BK 64
#define LDK 72         // BK + 8 bf16 pad: +16B per row -> 2-way (free) LDS conflicts, keeps 16B align

typedef __bf16 v8bf __attribute__((ext_vector_type(8)));
typedef float v4f  __attribute__((ext_vector_type(4)));

// ---------------- small utility kernels ----------------

__global__ void moe_zero_f4(float4* __restrict__ p, int n4){
  int i = blockIdx.x*blockDim.x + threadIdx.x;
  if (i < n4) p[i] = make_float4(0.f,0.f,0.f,0.f);
}

__global__ void moe_zero_i(int* __restrict__ p, int n){
  int i = threadIdx.x;
  if (i < n) p[i] = 0;
}

__global__ void moe_cast_x(const float* __restrict__ x, __hip_bfloat16* __restrict__ xb){
  int i = (blockIdx.x*blockDim.x + threadIdx.x)*4;
  float4 v = *reinterpret_cast<const float4*>(x + i);
  __hip_bfloat16 o[4];
  o[0]=__float2bfloat16(v.x); o[1]=__float2bfloat16(v.y);
  o[2]=__float2bfloat16(v.z); o[3]=__float2bfloat16(v.w);
  unsigned long long u; __builtin_memcpy(&u, o, 8);
  *reinterpret_cast<unsigned long long*>(xb + i) = u;
}

// transpose-cast fp32 -> bf16, B^T layout with zero padding.
// src (e<8): srcE + e*R*C ; (e==8): srcS.   dst[e] is [Cp][Rp]; dst[c][r] = (c<C && r<R) ? src[r][c] : 0
__global__ void moe_tcast(const float* __restrict__ srcE, const float* __restrict__ srcS,
                          __hip_bfloat16* __restrict__ dst, int R, int C, int Cp, int Rp){
  int e = blockIdx.z;
  const float* src = (e < NE) ? (srcE + (size_t)e*R*C) : srcS;
  __hip_bfloat16* d = dst + (size_t)e*Cp*Rp;
  __shared__ float tile[32][33];
  int c0 = blockIdx.x*32, r0 = blockIdx.y*32;
  #pragma unroll
  for (int i=0;i<4;i++){
    int r = r0 + threadIdx.y + i*8, c = c0 + threadIdx.x;
    float v = (r < R && c < C) ? src[(size_t)r*C + c] : 0.0f;
    tile[threadIdx.y + i*8][threadIdx.x] = v;
  }
  __syncthreads();
  #pragma unroll
  for (int i=0;i<4;i++){
    int c = c0 + threadIdx.y + i*8, r = r0 + threadIdx.x;
    if (c < Cp && r < Rp)
      d[(size_t)c*Rp + r] = __float2bfloat16(tile[threadIdx.x][threadIdx.y + i*8]);
  }
}

// ---------------- router: fp32 logits, softmax, top-2, bucket ----------------

__global__ __launch_bounds__(256) void moe_router(
    const float* __restrict__ x, const float* __restrict__ rw,
    float* __restrict__ topw, int* __restrict__ cnt, int* __restrict__ bucket){
  int wav = threadIdx.x >> 6, lane = threadIdx.x & 63;
  int t = blockIdx.x*4 + wav;
  const float* xr = x + (size_t)t*DIM;
  float a[NE];
  #pragma unroll
  for (int e=0;e<NE;e++) a[e]=0.f;
  for (int d0 = lane; d0 < DIM; d0 += 64){
    float xv = xr[d0];
    const float* rr = rw + d0*NE;
    #pragma unroll
    for (int e=0;e<NE;e++) a[e] += xv * rr[e];
  }
  #pragma unroll
  for (int e=0;e<NE;e++){
    float v = a[e];
    #pragma unroll
    for (int o=32;o>0;o>>=1) v += __shfl_xor(v, o);
    a[e]=v;
  }
  if (lane == 0){
    float m = a[0];
    for (int e=1;e<NE;e++) m = fmaxf(m, a[e]);
    float p[NE];
    for (int e=0;e<NE;e++) p[e] = expf(a[e]-m);
    int e0=0;
    for (int e=1;e<NE;e++) if (p[e] > p[e0]) e0=e;          // ties -> first idx (matches top_k)
    int e1 = (e0==0)?1:0;
    for (int e=0;e<NE;e++) if (e!=e0 && p[e] > p[e1]) e1=e;
    float ss = p[e0]+p[e1];
    topw[t*2]   = p[e0]/ss;
    topw[t*2+1] = p[e1]/ss;
    int p0 = atomicAdd(&cnt[e0],1); bucket[e0*16384 + p0] = t*2;
    int p1 = atomicAdd(&cnt[e1],1); bucket[e1*16384 + p1] = t*2+1;
  }
}

__global__ void moe_prefix(const int* __restrict__ cnt, int* __restrict__ base){
  if (threadIdx.x==0 && blockIdx.x==0){
    int b=0; base[0]=0;
    for (int e=0;e<NE;e++){ b += cnt[e]; base[e+1]=b; }  // base[8] == 16384 (every token -> 2 slots)
    base[9] = base[8] + NTOK;
  }
}

// rows [0,16384): expert assignments (grouped, contiguous per expert); rows [16384,24576): shared (weight 1)
__global__ void moe_fill(const int* __restrict__ cnt, const int* __restrict__ base,
                         const int* __restrict__ bucket, const float* __restrict__ topw,
                         int* __restrict__ row_token, float* __restrict__ row_weight){
  int idx = blockIdx.x*blockDim.x + threadIdx.x;   // 544*256 = 139264 = 8*16384 + 8192
  if (idx < NE*16384){
    int e = idx >> 14, p = idx & 16383;
    if (p < cnt[e]){
      int slot = bucket[idx];
      int row = base[e] + p;
      row_token[row]  = slot >> 1;
      row_weight[row] = topw[slot];
    }
  } else {
    int t = idx - NE*16384;
    row_token[16384 + t]  = t;
    row_weight[16384 + t] = 1.0f;
  }
}

// ---------------- GEMM1: g = silu(Xg @ w1) * (Xg @ w3), gathered A rows, dual acc ----------------
// grid (22, 128, 9); block 256 = 4 waves, each wave 64x64 of the 128x128 tile

__global__ __launch_bounds__(256, 2) void moe_gemm1(
    const __hip_bfloat16* __restrict__ xb,    // [NTOK][DIM]
    const __hip_bfloat16* __restrict__ w1t,   // [9][HID_PAD][DIM]  (B^T)
    const __hip_bfloat16* __restrict__ w3t,
    const int* __restrict__ row_token,
    const int* __restrict__ base_,            // [10]
    __hip_bfloat16* __restrict__ g)           // [NROWS][HID_PAD]
{
  int e   = blockIdx.z;
  int base = base_[e];
  int cnt  = base_[e+1] - base;
  int m0  = blockIdx.y * BM;
  if (m0 >= cnt) return;
  int n0  = blockIdx.x * BN;

  __shared__ __align__(16) unsigned short lA [BM][LDK];
  __shared__ __align__(16) unsigned short lB1[BN][LDK];
  __shared__ __align__(16) unsigned short lB3[BN][LDK];
  __shared__ int tok[BM];

  int tid = threadIdx.x;
  if (tid < BM){
    int r = m0 + tid;
    tok[tid] = row_token[base + (r < cnt ? r : m0)];
  }
  __syncthreads();

  const __hip_bfloat16* w1e = w1t + (size_t)e*HID_PAD*DIM;
  const __hip_bfloat16* w3e = w3t + (size_t)e*HID_PAD*DIM;

  // staging assignment: chunk c = tid + i*256 ; row = c>>3, col = (c&7)*8 (16B per chunk)
  const __hip_bfloat16* aSrc[4]; const __hip_bfloat16* b1Src[4]; const __hip_bfloat16* b3Src[4];
  unsigned short* aDst[4]; unsigned short* b1Dst[4]; unsigned short* b3Dst[4];
  #pragma unroll
  for (int i=0;i<4;i++){
    int c = tid + i*256;
    int row = c >> 3, col = (c & 7)*8;
    aSrc[i]  = xb  + (size_t)tok[row]*DIM + col;
    b1Src[i] = w1e + (size_t)(n0+row)*DIM + col;
    b3Src[i] = w3e + (size_t)(n0+row)*DIM + col;
    aDst[i]  = &lA [row][col];
    b1Dst[i] = &lB1[row][col];
    b3Dst[i] = &lB3[row][col];
  }

  int wav = tid >> 6, lane = tid & 63;
  int wm = (wav & 1)*64, wn = (wav >> 1)*64;
  int lm = lane & 15, lq = lane >> 4;

  v4f acc1[4][4], acc3[4][4];
  v4f vz = {0.f,0.f,0.f,0.f};
  #pragma unroll
  for (int i=0;i<4;i++)
    #pragma unroll
    for (int j=0;j<4;j++){ acc1[i][j]=vz; acc3[i][j]=vz; }

  for (int k0 = 0; k0 < DIM; k0 += BK){
    #pragma unroll
    for (int i=0;i<4;i++){
      *reinterpret_cast<uint4*>(aDst[i])  = *reinterpret_cast<const uint4*>(aSrc[i]  + k0);
      *reinterpret_cast<uint4*>(b1Dst[i]) = *reinterpret_cast<const uint4*>(b1Src[i] + k0);
      *reinterpret_cast<uint4*>(b3Dst[i]) = *reinterpret_cast<const uint4*>(b3Src[i] + k0);
    }
    __syncthreads();
    #pragma unroll
    for (int ks=0; ks<2; ks++){
      v8bf af[4], b1f[4], b3f[4];
      #pragma unroll
      for (int i=0;i<4;i++){
        af[i]  = *reinterpret_cast<const v8bf*>(&lA [wm + i*16 + lm][ks*32 + lq*8]);
        b1f[i] = *reinterpret_cast<const v8bf*>(&lB1[wn + i*16 + lm][ks*32 + lq*8]);
        b3f[i] = *reinterpret_cast<const v8bf*>(&lB3[wn + i*16 + lm][ks*32 + lq*8]);
      }
      #pragma unroll
      for (int i=0;i<4;i++)
        #pragma unroll
        for (int j=0;j<4;j++){
          acc1[i][j] = __builtin_amdgcn_mfma_f32_16x16x32_bf16(af[i], b1f[j], acc1[i][j], 0,0,0);
          acc3[i][j] = __builtin_amdgcn_mfma_f32_16x16x32_bf16(af[i], b3f[j], acc3[i][j], 0,0,0);
        }
    }
    __syncthreads();
  }

  // epilogue: D layout col=lane&15, row=(lane>>4)*4+reg  [m89-verified]
  #pragma unroll
  for (int i=0;i<4;i++){
    #pragma unroll
    for (int r=0;r<4;r++){
      int ml = wm + i*16 + lq*4 + r;
      if (m0 + ml < cnt){
        size_t grow = (size_t)(base + m0 + ml) * HID_PAD;
        #pragma unroll
        for (int j=0;j<4;j++){
          float s1 = acc1[i][j][r];
          float s3 = acc3[i][j][r];
          float gv = (s1 / (1.0f + __expf(-s1))) * s3;   // silu(s1)*s3
          g[grow + n0 + wn + j*16 + lm] = __float2bfloat16(gv);
        }
      }
    }
  }
}

// ---------------- GEMM2: out[token] += weight * (g @ w2) ----------------
// grid (16, 128, 9)

__global__ __launch_bounds__(256, 2) void moe_gemm2(
    const __hip_bfloat16* __restrict__ g,     // [NROWS][HID_PAD]
    const __hip_bfloat16* __restrict__ w2t,   // [9][DIM][HID_PAD]  (B^T)
    const int* __restrict__ row_token,
    const float* __restrict__ row_weight,
    const int* __restrict__ base_,
    float* __restrict__ out)                  // [NTOK][DIM], pre-zeroed
{
  int e = blockIdx.z;
  int base = base_[e];
  int cnt  = base_[e+1] - base;
  int m0 = blockIdx.y * BM;
  if (m0 >= cnt) return;
  int n0 = blockIdx.x * BN;

  __shared__ __align__(16) unsigned short lA[BM][LDK];
  __shared__ __align__(16) unsigned short lB[BN][LDK];
  __shared__ int   tok[BM];
  __shared__ float wgt[BM];

  int tid = threadIdx.x;
  if (tid < BM){
    int r = m0 + tid;
    bool v = (r < cnt);
    tok[tid] = v ? row_token[base + r]  : 0;
    wgt[tid] = v ? row_weight[base + r] : 0.0f;
  }
  __syncthreads();

  const __hip_bfloat16* w2e = w2t + (size_t)e*DIM*HID_PAD;

  const __hip_bfloat16* aSrc[4]; const __hip_bfloat16* bSrc[4];
  unsigned short* aDst[4]; unsigned short* bDst[4];
  #pragma unroll
  for (int i=0;i<4;i++){
    int c = tid + i*256;
    int row = c >> 3, col = (c & 7)*8;
    // A rows are contiguous in g (grouped layout); over-reach rows land in the next
    // group's valid rows (finite data), results discarded at store time.
    aSrc[i] = g   + (size_t)(base + m0 + row)*HID_PAD + col;
    bSrc[i] = w2e + (size_t)(n0 + row)*HID_PAD + col;
    aDst[i] = &lA[row][col];
    bDst[i] = &lB[row][col];
  }

  int wav = tid >> 6, lane = tid & 63;
  int wm = (wav & 1)*64, wn = (wav >> 1)*64;
  int lm = lane & 15, lq = lane >> 4;

  v4f acc[4][4];
  v4f vz = {0.f,0.f,0.f,0.f};
  #pragma unroll
  for (int i=0;i<4;i++)
    #pragma unroll
    for (int j=0;j<4;j++) acc[i][j]=vz;

  for (int k0 = 0; k0 < HID_PAD; k0 += BK){   // 44 iters; pad region is zeros on both sides
    #pragma unroll
    for (int i=0;i<4;i++){
      *reinterpret_cast<uint4*>(aDst[i]) = *reinterpret_cast<const uint4*>(aSrc[i] + k0);
      *reinterpret_cast<uint4*>(bDst[i]) = *reinterpret_cast<const uint4*>(bSrc[i] + k0);
    }
    __syncthreads();
    #pragma unroll
    for (int ks=0; ks<2; ks++){
      v8bf af[4], bf[4];
      #pragma unroll
      for (int i=0;i<4;i++){
        af[i] = *reinterpret_cast<const v8bf*>(&lA[wm + i*16 + lm][ks*32 + lq*8]);
        bf[i] = *reinterpret_cast<const v8bf*>(&lB[wn + i*16 + lm][ks*32 + lq*8]);
      }
      #pragma unroll
      for (int i=0;i<4;i++)
        #pragma unroll
        for (int j=0;j<4;j++)
          acc[i][j] = __builtin_amdgcn_mfma_f32_16x16x32_bf16(af[i], bf[j], acc[i][j], 0,0,0);
    }
    __syncthreads();
  }

  #pragma unroll
  for (int i=0;i<4;i++){
    #pragma unroll
    for (int r=0;r<4;r++){
      int ml = wm + i*16 + lq*4 + r;
      if (m0 + ml < cnt){
        int   t  = tok[ml];
        float wv = wgt[ml];
        #pragma unroll
        for (int j=0;j<4;j++){
          atomicAdd(out + (size_t)t*DIM + n0 + wn + j*16 + lm, wv * acc[i][j][r]);
        }
      }
    }
  }
}

// ---------------- host launch ----------------

extern "C" void kernel_launch(void* const* d_in, const int* in_sizes, int n_in,
                              void* d_out, int out_size, void* d_ws, size_t ws_size,
                              hipStream_t stream) {
  const float* x   = (const float*)d_in[0];
  const float* rw  = (const float*)d_in[1];
  const float* sw1 = (const float*)d_in[2];
  const float* sw2 = (const float*)d_in[3];
  const float* sw3 = (const float*)d_in[4];
  const float* ew1 = (const float*)d_in[5];
  const float* ew2 = (const float*)d_in[6];
  const float* ew3 = (const float*)d_in[7];
  float* out = (float*)d_out;

  char* ws = (char*)d_ws;
  size_t off = 0;
  auto nxt = [&](size_t b) -> char* {
    char* p = ws + off; off += (b + 255) & ~(size_t)255; return p;
  };
  __hip_bfloat16* xb  = (__hip_bfloat16*)nxt((size_t)NTOK*DIM*2);          // 33.5 MB
  __hip_bfloat16* w1t = (__hip_bfloat16*)nxt((size_t)9*HID_PAD*DIM*2);     // 103.8 MB
  __hip_bfloat16* w3t = (__hip_bfloat16*)nxt((size_t)9*HID_PAD*DIM*2);
  __hip_bfloat16* w2t = (__hip_bfloat16*)nxt((size_t)9*DIM*HID_PAD*2);
  __hip_bfloat16* g   = (__hip_bfloat16*)nxt((size_t)NROWS*HID_PAD*2);     // 138.4 MB
  float* topw      = (float*)nxt(16384*4);
  int*   cnt       = (int*)  nxt(32);
  int*   base_     = (int*)  nxt(64);
  int*   bucket    = (int*)  nxt(NE*16384*4);
  int*   row_token = (int*)  nxt(NROWS*4);
  float* row_weight= (float*)nxt(NROWS*4);

  if (off > ws_size) {
    fprintf(stderr, "MoE kernel: ws too small (%zu needed, %zu given)\n", off, ws_size);
    return;
  }

  moe_zero_f4<<<16384, 256, 0, stream>>>((float4*)out, NTOK*DIM/4);
  moe_zero_i<<<1, 32, 0, stream>>>(cnt, NE);
  moe_cast_x<<<16384, 256, 0, stream>>>(x, xb);

  dim3 tb(32,8);
  moe_tcast<<<dim3(88,64,9), tb, 0, stream>>>(ew1, sw1, w1t, DIM, HID, HID_PAD, DIM);
  moe_tcast<<<dim3(88,64,9), tb, 0, stream>>>(ew3, sw3, w3t, DIM, HID, HID_PAD, DIM);
  moe_tcast<<<dim3(64,88,9), tb, 0, stream>>>(ew2, sw2, w2t, HID, DIM, DIM, HID_PAD);

  moe_router<<<NTOK/4, 256, 0, stream>>>(x, rw, topw, cnt, bucket);
  moe_prefix<<<1, 1, 0, stream>>>(cnt, base_);
  moe_fill<<<544, 256, 0, stream>>>(cnt, base_, bucket, topw, row_token, row_weight);

  moe_gemm1<<<dim3(22,128,9), 256, 0, stream>>>(xb, w1t, w3t, row_token, base_, g);
  moe_gemm2<<<dim3(16,128,9), 256, 0, stream>>>(g, w2t, row_token, row_weight, base_, out);
}

// Round 2
// 1863.886 us; speedup vs baseline: 1.0729x; 1.0729x over previous
//
#include <hip/hip_runtime.h>
#include <hip/hip_bf16.h>
#include <stdio.h>

#define DIM 2048
#define HID 2730
#define HID_PAD 2816   // 22*128, zero-padded
#define NE 8
#define NTOK 8192      // B*T
#define NROWS 24576    // 16384 expert-assignment rows + 8192 shared rows
#define BM 128
#define BN 128
#define BK 64

typedef __bf16 v8bf __attribute__((ext_vector_type(8)));
typedef float v4f  __attribute__((ext_vector_type(4)));

// async global->LDS, 16B per lane, wave-uniform LDS base + lane*16 (m97/m104 semantics)
__device__ __forceinline__ void gload16(const void* g, void* l){
  __builtin_amdgcn_global_load_lds((const __attribute__((address_space(1))) void*)g,
                                   (__attribute__((address_space(3))) void*)l, 16, 0, 0);
}

// ---------------- small utility kernels ----------------

__global__ void moe_zero_i(int* __restrict__ p, int n){
  int i = threadIdx.x;
  if (i < n) p[i] = 0;
}

__global__ void moe_cast_x(const float* __restrict__ x, __hip_bfloat16* __restrict__ xb){
  int i = (blockIdx.x*blockDim.x + threadIdx.x)*4;
  float4 v = *reinterpret_cast<const float4*>(x + i);
  __hip_bfloat16 o[4];
  o[0]=__float2bfloat16(v.x); o[1]=__float2bfloat16(v.y);
  o[2]=__float2bfloat16(v.z); o[3]=__float2bfloat16(v.w);
  unsigned long long u; __builtin_memcpy(&u, o, 8);
  *reinterpret_cast<unsigned long long*>(xb + i) = u;
}

// transpose-cast fp32 -> bf16, B^T layout with zero padding.
__global__ void moe_tcast(const float* __restrict__ srcE, const float* __restrict__ srcS,
                          __hip_bfloat16* __restrict__ dst, int R, int C, int Cp, int Rp){
  int e = blockIdx.z;
  const float* src = (e < NE) ? (srcE + (size_t)e*R*C) : srcS;
  __hip_bfloat16* d = dst + (size_t)e*Cp*Rp;
  __shared__ float tile[32][33];
  int c0 = blockIdx.x*32, r0 = blockIdx.y*32;
  #pragma unroll
  for (int i=0;i<4;i++){
    int r = r0 + threadIdx.y + i*8, c = c0 + threadIdx.x;
    float v = (r < R && c < C) ? src[(size_t)r*C + c] : 0.0f;
    tile[threadIdx.y + i*8][threadIdx.x] = v;
  }
  __syncthreads();
  #pragma unroll
  for (int i=0;i<4;i++){
    int c = c0 + threadIdx.y + i*8, r = r0 + threadIdx.x;
    if (c < Cp && r < Rp)
      d[(size_t)c*Rp + r] = __float2bfloat16(tile[threadIdx.x][threadIdx.y + i*8]);
  }
}

// ---------------- router: fp32 logits, softmax, top-2, bucket ----------------

__global__ __launch_bounds__(256) void moe_router(
    const float* __restrict__ x, const float* __restrict__ rw,
    float* __restrict__ topw, int* __restrict__ cnt, int* __restrict__ bucket){
  int wav = threadIdx.x >> 6, lane = threadIdx.x & 63;
  int t = blockIdx.x*4 + wav;
  const float* xr = x + (size_t)t*DIM;
  float a[NE];
  #pragma unroll
  for (int e=0;e<NE;e++) a[e]=0.f;
  for (int d0 = lane; d0 < DIM; d0 += 64){
    float xv = xr[d0];
    const float* rr = rw + d0*NE;
    #pragma unroll
    for (int e=0;e<NE;e++) a[e] += xv * rr[e];
  }
  #pragma unroll
  for (int e=0;e<NE;e++){
    float v = a[e];
    #pragma unroll
    for (int o=32;o>0;o>>=1) v += __shfl_xor(v, o);
    a[e]=v;
  }
  if (lane == 0){
    float m = a[0];
    for (int e=1;e<NE;e++) m = fmaxf(m, a[e]);
    float p[NE];
    for (int e=0;e<NE;e++) p[e] = expf(a[e]-m);
    int e0=0;
    for (int e=1;e<NE;e++) if (p[e] > p[e0]) e0=e;          // ties -> first idx (matches top_k)
    int e1 = (e0==0)?1:0;
    for (int e=0;e<NE;e++) if (e!=e0 && p[e] > p[e1]) e1=e;
    float ss = p[e0]+p[e1];
    topw[t*2]   = p[e0]/ss;
    topw[t*2+1] = p[e1]/ss;
    int p0 = atomicAdd(&cnt[e0],1); bucket[e0*16384 + p0] = t*2;
    int p1 = atomicAdd(&cnt[e1],1); bucket[e1*16384 + p1] = t*2+1;
  }
}

__global__ void moe_prefix(const int* __restrict__ cnt, int* __restrict__ base){
  if (threadIdx.x==0 && blockIdx.x==0){
    int b=0; base[0]=0;
    for (int e=0;e<NE;e++){ b += cnt[e]; base[e+1]=b; }  // base[8] == 16384
    base[9] = base[8] + NTOK;
  }
}

// rows [0,16384): expert assignments (grouped); rows [16384,24576): shared (weight 1)
// inv[slot] = row, for the combine kernel
__global__ void moe_fill(const int* __restrict__ cnt, const int* __restrict__ base,
                         const int* __restrict__ bucket, const float* __restrict__ topw,
                         int* __restrict__ row_token, float* __restrict__ row_weight,
                         int* __restrict__ inv){
  int idx = blockIdx.x*blockDim.x + threadIdx.x;   // 544*256 = 8*16384 + 8192
  if (idx < NE*16384){
    int e = idx >> 14, p = idx & 16383;
    if (p < cnt[e]){
      int slot = bucket[idx];
      int row = base[e] + p;
      row_token[row]  = slot >> 1;
      row_weight[row] = topw[slot];
      inv[slot] = row;
    }
  } else {
    int t = idx - NE*16384;
    row_token[16384 + t]  = t;
    row_weight[16384 + t] = 1.0f;
  }
}

// ---------------- GEMM1: g = silu(Xg @ w1) * (Xg @ w3) ----------------
// global_load_lds staging, XOR-swizzled LDS (chunk' = chunk ^ (row&7)), no padding.
// grid (22, 128, 9); block 256 = 4 waves, each wave 64x64 of the 128x128 tile

__global__ __launch_bounds__(256, 2) void moe_gemm1(
    const __hip_bfloat16* __restrict__ xb,    // [NTOK][DIM]
    const __hip_bfloat16* __restrict__ w1t,   // [9][HID_PAD][DIM]  (B^T)
    const __hip_bfloat16* __restrict__ w3t,
    const int* __restrict__ row_token,
    const int* __restrict__ base_,            // [10]
    __hip_bfloat16* __restrict__ g)           // [NROWS][HID_PAD]
{
  int e   = blockIdx.z;
  int base = base_[e];
  int cnt  = base_[e+1] - base;
  int m0  = blockIdx.y * BM;
  if (m0 >= cnt) return;
  int n0  = blockIdx.x * BN;

  __shared__ __align__(16) unsigned short lA [BM][BK];   // 16 KB each, unpadded (DMA dest)
  __shared__ __align__(16) unsigned short lB1[BN][BK];
  __shared__ __align__(16) unsigned short lB3[BN][BK];
  __shared__ int tok[BM];

  int tid = threadIdx.x;
  if (tid < BM){
    int r = m0 + tid;
    tok[tid] = row_token[base + (r < cnt ? r : m0)];
  }
  __syncthreads();

  const __hip_bfloat16* w1e = w1t + (size_t)e*HID_PAD*DIM;
  const __hip_bfloat16* w3e = w3t + (size_t)e*HID_PAD*DIM;

  int wav = tid >> 6, lane = tid & 63;

  // per-issue source pointers (swizzled chunk) + wave-uniform LDS bases
  const __hip_bfloat16 *aS[4], *b1S[4], *b3S[4];
  unsigned short *aL[4], *b1L[4], *b3L[4];
  #pragma unroll
  for (int i=0;i<4;i++){
    int c = wav*256 + i*64 + lane;          // chunk index in [0,1024), 16B chunks
    int r = c >> 3, p = c & 7, q = p ^ (r & 7);
    aS[i]  = xb  + (size_t)tok[r]*DIM + q*8;
    b1S[i] = w1e + (size_t)(n0+r)*DIM + q*8;
    b3S[i] = w3e + (size_t)(n0+r)*DIM + q*8;
    int c0 = wav*256 + i*64;                // wave-uniform
    aL[i]  = &lA [0][0] + c0*8;
    b1L[i] = &lB1[0][0] + c0*8;
    b3L[i] = &lB3[0][0] + c0*8;
  }

  int wm = (wav & 1)*64, wn = (wav >> 1)*64;
  int lm = lane & 15, lq = lane >> 4;
  int sw = lm & 7;                           // read-side swizzle key

  v4f acc1[4][4], acc3[4][4];
  v4f vz = {0.f,0.f,0.f,0.f};
  #pragma unroll
  for (int i=0;i<4;i++)
    #pragma unroll
    for (int j=0;j<4;j++){ acc1[i][j]=vz; acc3[i][j]=vz; }

  for (int k0 = 0; k0 < DIM; k0 += BK){
    #pragma unroll
    for (int i=0;i<4;i++){
      gload16(aS[i]  + k0, aL[i]);
      gload16(b1S[i] + k0, b1L[i]);
      gload16(b3S[i] + k0, b3L[i]);
    }
    __syncthreads();   // drains vmcnt (global_load_lds) per compiler barrier semantics
    #pragma unroll
    for (int ks=0; ks<2; ks++){
      v8bf af[4], b1f[4], b3f[4];
      #pragma unroll
      for (int i=0;i<4;i++){
        int qa = ((ks*4 + lq) ^ sw)*8;
        af[i]  = *reinterpret_cast<const v8bf*>(&lA [wm + i*16 + lm][qa]);
        b1f[i] = *reinterpret_cast<const v8bf*>(&lB1[wn + i*16 + lm][qa]);
        b3f[i] = *reinterpret_cast<const v8bf*>(&lB3[wn + i*16 + lm][qa]);
      }
      #pragma unroll
      for (int i=0;i<4;i++)
        #pragma unroll
        for (int j=0;j<4;j++){
          acc1[i][j] = __builtin_amdgcn_mfma_f32_16x16x32_bf16(af[i], b1f[j], acc1[i][j], 0,0,0);
          acc3[i][j] = __builtin_amdgcn_mfma_f32_16x16x32_bf16(af[i], b3f[j], acc3[i][j], 0,0,0);
        }
    }
    __syncthreads();
  }

  // epilogue: D layout col=lane&15, row=(lane>>4)*4+reg  [m89-verified]
  #pragma unroll
  for (int i=0;i<4;i++){
    #pragma unroll
    for (int r=0;r<4;r++){
      int ml = wm + i*16 + lq*4 + r;
      if (m0 + ml < cnt){
        size_t grow = (size_t)(base + m0 + ml) * HID_PAD;
        #pragma unroll
        for (int j=0;j<4;j++){
          float s1 = acc1[i][j][r];
          float s3 = acc3[i][j][r];
          float gv = (s1 / (1.0f + __expf(-s1))) * s3;   // silu(s1)*s3
          g[grow + n0 + wn + j*16 + lm] = __float2bfloat16(gv);
        }
      }
    }
  }
}

// ---------------- GEMM2: y[row] = weight * (g[row] @ w2), plain stores ----------------
// grid (16, 128, 9)

__global__ __launch_bounds__(256, 3) void moe_gemm2(
    const __hip_bfloat16* __restrict__ g,     // [NROWS][HID_PAD]
    const __hip_bfloat16* __restrict__ w2t,   // [9][DIM][HID_PAD]  (B^T)
    const float* __restrict__ row_weight,
    const int* __restrict__ base_,
    float* __restrict__ y)                    // [NROWS][DIM] scratch (aliases w1t/w3t)
{
  int e = blockIdx.z;
  int base = base_[e];
  int cnt  = base_[e+1] - base;
  int m0 = blockIdx.y * BM;
  if (m0 >= cnt) return;
  int n0 = blockIdx.x * BN;

  __shared__ __align__(16) unsigned short lA[BM][BK];
  __shared__ __align__(16) unsigned short lB[BN][BK];
  __shared__ float wgt[BM];

  int tid = threadIdx.x;
  if (tid < BM){
    int r = m0 + tid;
    wgt[tid] = (r < cnt) ? row_weight[base + r] : 0.0f;
  }
  __syncthreads();

  const __hip_bfloat16* w2e = w2t + (size_t)e*DIM*HID_PAD;

  int wav = tid >> 6, lane = tid & 63;

  const __hip_bfloat16 *aS[4], *bS[4];
  unsigned short *aL[4], *bL[4];
  #pragma unroll
  for (int i=0;i<4;i++){
    int c = wav*256 + i*64 + lane;
    int r = c >> 3, p = c & 7, q = p ^ (r & 7);
    // A over-reach rows land in the next group's valid rows; results discarded at store
    aS[i] = g   + (size_t)(base + m0 + r)*HID_PAD + q*8;
    bS[i] = w2e + (size_t)(n0 + r)*HID_PAD + q*8;
    int c0 = wav*256 + i*64;
    aL[i] = &lA[0][0] + c0*8;
    bL[i] = &lB[0][0] + c0*8;
  }

  int wm = (wav & 1)*64, wn = (wav >> 1)*64;
  int lm = lane & 15, lq = lane >> 4;
  int sw = lm & 7;

  v4f acc[4][4];
  v4f vz = {0.f,0.f,0.f,0.f};
  #pragma unroll
  for (int i=0;i<4;i++)
    #pragma unroll
    for (int j=0;j<4;j++) acc[i][j]=vz;

  for (int k0 = 0; k0 < HID_PAD; k0 += BK){   // 44 iters; pad region zero on both sides
    #pragma unroll
    for (int i=0;i<4;i++){
      gload16(aS[i] + k0, aL[i]);
      gload16(bS[i] + k0, bL[i]);
    }
    __syncthreads();
    #pragma unroll
    for (int ks=0; ks<2; ks++){
      v8bf af[4], bf[4];
      #pragma unroll
      for (int i=0;i<4;i++){
        int qa = ((ks*4 + lq) ^ sw)*8;
        af[i] = *reinterpret_cast<const v8bf*>(&lA[wm + i*16 + lm][qa]);
        bf[i] = *reinterpret_cast<const v8bf*>(&lB[wn + i*16 + lm][qa]);
      }
      #pragma unroll
      for (int i=0;i<4;i++)
        #pragma unroll
        for (int j=0;j<4;j++)
          acc[i][j] = __builtin_amdgcn_mfma_f32_16x16x32_bf16(af[i], bf[j], acc[i][j], 0,0,0);
    }
    __syncthreads();
  }

  #pragma unroll
  for (int i=0;i<4;i++){
    #pragma unroll
    for (int r=0;r<4;r++){
      int ml = wm + i*16 + lq*4 + r;
      if (m0 + ml < cnt){
        float wv = wgt[ml];
        size_t yrow = (size_t)(base + m0 + ml) * DIM;
        #pragma unroll
        for (int j=0;j<4;j++)
          y[yrow + n0 + wn + j*16 + lm] = wv * acc[i][j][r];
      }
    }
  }
}

// ---------------- combine: out[t] = y[shared_t] + y[r0] + y[r1] (y pre-weighted) ----------------

__global__ __launch_bounds__(256) void moe_combine(
    const float4* __restrict__ y, const int* __restrict__ inv, float4* __restrict__ out){
  int idx = blockIdx.x*blockDim.x + threadIdx.x;   // 8192 * 512
  int t = idx >> 9, d = idx & 511;
  float4 s = y[(((size_t)16384 + t) << 9) + d];
  int r0 = inv[t*2], r1 = inv[t*2+1];
  float4 a = y[((size_t)r0 << 9) + d];
  float4 b = y[((size_t)r1 << 9) + d];
  s.x += a.x + b.x; s.y += a.y + b.y; s.z += a.z + b.z; s.w += a.w + b.w;
  out[idx] = s;
}

// ---------------- host launch ----------------

extern "C" void kernel_launch(void* const* d_in, const int* in_sizes, int n_in,
                              void* d_out, int out_size, void* d_ws, size_t ws_size,
                              hipStream_t stream) {
  const float* x   = (const float*)d_in[0];
  const float* rw  = (const float*)d_in[1];
  const float* sw1 = (const float*)d_in[2];
  const float* sw2 = (const float*)d_in[3];
  const float* sw3 = (const float*)d_in[4];
  const float* ew1 = (const float*)d_in[5];
  const float* ew2 = (const float*)d_in[6];
  const float* ew3 = (const float*)d_in[7];
  float* out = (float*)d_out;

  char* ws = (char*)d_ws;
  size_t off = 0;
  auto nxt = [&](size_t b) -> char* {
    char* p = ws + off; off += (b + 255) & ~(size_t)255; return p;
  };
  __hip_bfloat16* xb  = (__hip_bfloat16*)nxt((size_t)NTOK*DIM*2);          // 33.5 MB
  __hip_bfloat16* w1t = (__hip_bfloat16*)nxt((size_t)9*HID_PAD*DIM*2);     // 103.8 MB
  __hip_bfloat16* w3t = (__hip_bfloat16*)nxt((size_t)9*HID_PAD*DIM*2);     // 103.8 MB
  __hip_bfloat16* w2t = (__hip_bfloat16*)nxt((size_t)9*DIM*HID_PAD*2);     // 103.8 MB
  __hip_bfloat16* g   = (__hip_bfloat16*)nxt((size_t)NROWS*HID_PAD*2);     // 138.4 MB
  float* topw      = (float*)nxt(16384*4);
  int*   cnt       = (int*)  nxt(32);
  int*   base_     = (int*)  nxt(64);
  int*   bucket    = (int*)  nxt(NE*16384*4);
  int*   row_token = (int*)  nxt(NROWS*4);
  float* row_weight= (float*)nxt(NROWS*4);
  int*   inv       = (int*)  nxt(16384*4);

  // y scratch (201.3 MB fp32) aliases w1t+w3t (207.6 MB) — dead after gemm1,
  // written by gemm2, read by combine; stream-ordered so no hazard.
  static_assert((size_t)NROWS*DIM*4 <= 2*((size_t)9*HID_PAD*DIM*2), "y alias overflow");
  float* y = (float*)w1t;

  if (off > ws_size) {
    fprintf(stderr, "MoE kernel: ws too small (%zu needed, %zu given)\n", off, ws_size);
    return;
  }

  moe_zero_i<<<1, 32, 0, stream>>>(cnt, NE);
  moe_cast_x<<<16384, 256, 0, stream>>>(x, xb);

  dim3 tb(32,8);
  moe_tcast<<<dim3(88,64,9), tb, 0, stream>>>(ew1, sw1, w1t, DIM, HID, HID_PAD, DIM);
  moe_tcast<<<dim3(88,64,9), tb, 0, stream>>>(ew3, sw3, w3t, DIM, HID, HID_PAD, DIM);
  moe_tcast<<<dim3(64,88,9), tb, 0, stream>>>(ew2, sw2, w2t, HID, DIM, DIM, HID_PAD);

  moe_router<<<NTOK/4, 256, 0, stream>>>(x, rw, topw, cnt, bucket);
  moe_prefix<<<1, 1, 0, stream>>>(cnt, base_);
  moe_fill<<<544, 256, 0, stream>>>(cnt, base_, bucket, topw, row_token, row_weight, inv);

  moe_gemm1<<<dim3(22,128,9), 256, 0, stream>>>(xb, w1t, w3t, row_token, base_, g);
  moe_gemm2<<<dim3(16,128,9), 256, 0, stream>>>(g, w2t, row_weight, base_, y);
  moe_combine<<<16384, 256, 0, stream>>>((const float4*)y, inv, (float4*)out);
}